// Round 1
// baseline (399.778 us; speedup 1.0000x reference)
//
#include <hip/hip_runtime.h>
#include <hip/hip_bf16.h>

#define B_DIM 4
#define C_DIM 512
#define L_DIM 2048
#define KN 4
#define MAXKS 9

__device__ inline float bf2f(unsigned short u){ return __uint_as_float(((unsigned)u)<<16); }
__device__ inline unsigned short f2bf(float f){
  unsigned u = __float_as_uint(f);
  unsigned r = (u + 0x7fffu + ((u>>16)&1u))>>16;
  return (unsigned short)r;
}

// Reduce a float4 across the 256-thread block; every thread returns the total.
__device__ float4 block_reduce4(float4 v, float* rb, int tid){
  #pragma unroll
  for (int off=32; off>=1; off>>=1){
    v.x += __shfl_xor(v.x, off);
    v.y += __shfl_xor(v.y, off);
    v.z += __shfl_xor(v.z, off);
    v.w += __shfl_xor(v.w, off);
  }
  __syncthreads();               // protect rb against previous consumers
  int wv = tid>>6;
  if ((tid&63)==0){ rb[wv*4+0]=v.x; rb[wv*4+1]=v.y; rb[wv*4+2]=v.z; rb[wv*4+3]=v.w; }
  __syncthreads();
  float4 r;
  r.x = rb[0]+rb[4]+rb[8]+rb[12];
  r.y = rb[1]+rb[5]+rb[9]+rb[13];
  r.z = rb[2]+rb[6]+rb[10]+rb[14];
  r.w = rb[3]+rb[7]+rb[11]+rb[15];
  return r;
}

// In-place 512-point radix-2 DIT FFT on LDS arrays; 256 threads = 256 butterflies/stage.
// Twiddle table tw[j] = e^{-2*pi*i*j/512}. tsgn=+1 forward, -1 inverse (unscaled).
__device__ void fft512(float* re, float* im, const float* twr, const float* twi,
                       float tsgn, int tid){
  __syncthreads();
  #pragma unroll
  for (int rep=0; rep<2; ++rep){
    int i = tid + rep*256;
    int j = (int)(__brev((unsigned)i) >> 23);
    if (i < j){
      float tr = re[i]; re[i]=re[j]; re[j]=tr;
      float ti = im[i]; im[i]=im[j]; im[j]=ti;
    }
  }
  __syncthreads();
  #pragma unroll
  for (int s=1; s<=9; ++s){
    int half = 1<<(s-1);
    int blk = tid >> (s-1);
    int pos = tid & (half-1);
    int i0 = (blk<<s) + pos;
    int i1 = i0 + half;
    int tix = pos << (9-s);
    float wr = twr[tix], wi = tsgn*twi[tix];
    float ar=re[i0], ai=im[i0], br=re[i1], bi=im[i1];
    float tr = br*wr - bi*wi;
    float ti = br*wi + bi*wr;
    re[i0]=ar+tr; im[i0]=ai+ti;
    re[i1]=ar-tr; im[i1]=ai-ti;
    __syncthreads();
  }
}

__global__ __launch_bounds__(256) void col_kernel(
    const float* __restrict__ x, const float* __restrict__ q,
    const float* __restrict__ sigmas, const float* __restrict__ centers,
    const int* __restrict__ ksp,
    unsigned short* __restrict__ outs, float* __restrict__ qmean)
{
  __shared__ float qre[512], qim[512], vre[512], vim[512];
  __shared__ float xcol[MAXKS][512];
  __shared__ float twr[256], twi[256];
  __shared__ float kern[KN][MAXKS];
  __shared__ float rb[16];

  int tid = threadIdx.x;
  int l = blockIdx.x;
  int b = blockIdx.y;
  int ks = ksp[0];
  int pad = ks>>1;

  { // twiddles
    float ang = -2.0f*3.14159265358979323846f*(float)tid/512.0f;
    float s,c; sincosf(ang,&s,&c);
    twr[tid]=c; twi[tid]=s;
  }
  if (tid < KN*ks){ // gaussian kernels (pre-normalization)
    int k = tid/ks, t = tid - k*ks;
    float half = 0.5f*(float)(ks-1);
    float xs = (float)t - half;
    float d = (xs - centers[k])/(sigmas[k]+0.001f);
    kern[k][t] = expf(-0.5f*d*d);
  }
  __syncthreads();
  if (tid < KN){
    float s=0.f;
    for (int t=0;t<ks;++t) s += kern[tid][t];
    float inv = 1.0f/(s+0.01f);
    for (int t=0;t<ks;++t) kern[tid][t] *= inv;
  }
  // load q column and the ks x-columns (edge-clamped)
  for (int c=tid; c<512; c+=256){
    const float* rowq = q + ((size_t)(b*512+c))*2048;
    qre[c] = rowq[l]; qim[c] = 0.f;
    const float* rowx = x + ((size_t)(b*512+c))*2048;
    for (int t=0;t<ks;++t){
      int li = l + t - pad;
      li = li < 0 ? 0 : (li > 2047 ? 2047 : li);
      xcol[t][c] = rowx[li];
    }
  }
  fft512(qre,qim,twr,twi,1.0f,tid);          // qf
  if (tid==0) qmean[b*2048+l] = qre[0]*(1.0f/512.0f);

  // S1 = sum qf, S2 = sum qf^2 (complex)
  float4 a4 = make_float4(0,0,0,0);
  #pragma unroll
  for (int rep=0; rep<2; ++rep){
    int c = tid + rep*256;
    float re=qre[c], im=qim[c];
    a4.x += re; a4.y += im;
    a4.z += re*re - im*im;
    a4.w += 2.f*re*im;
  }
  a4 = block_reduce4(a4, rb, tid);
  float myr = a4.x*(1.f/512.f), myi = a4.y*(1.f/512.f);
  float bsr = a4.z - (a4.x*myr - a4.y*myi);   // b_sum = S2 - S1*my
  float bsi = a4.w - (a4.x*myi + a4.y*myr);

  for (int k=0;k<KN;++k){
    __syncthreads();
    for (int c=tid;c<512;c+=256){ // depthwise conv from staged x columns
      float s = 0.f;
      for (int t=0;t<ks;++t) s += xcol[t][c]*kern[k][t];
      vre[c]=s; vim[c]=0.f;
    }
    fft512(vre,vim,twr,twi,1.0f,tid);        // vf
    float4 v4 = make_float4(0,0,0,0);
    #pragma unroll
    for (int rep=0; rep<2; ++rep){
      int c = tid + rep*256;
      float re=vre[c], im=vim[c];
      v4.x += re; v4.y += im;
      v4.z += re*re - im*im;
      v4.w += 2.f*re*im;
    }
    v4 = block_reduce4(v4, rb, tid);
    float mxr = v4.x*(1.f/512.f), mxi = v4.y*(1.f/512.f);
    float asr = v4.z - (v4.x*mxr - v4.y*mxi);
    float asi = v4.w - (v4.x*mxi + v4.y*mxr);
    // z = a_sum*b_sum + 1e-4 ; denom = csqrt(z) ; inv = conj(denom)/|denom|^2
    float zr = asr*bsr - asi*bsi + 1.0e-4f;
    float zi = asr*bsi + asi*bsr;
    float rmag = sqrtf(zr*zr+zi*zi);
    float dr = sqrtf(fmaxf(0.5f*(rmag+zr),0.f));
    float di = sqrtf(fmaxf(0.5f*(rmag-zr),0.f));
    di = (zi < 0.f) ? -di : di;
    float den = dr*dr + di*di;
    float invr = 0.f, invi = 0.f;
    if (den > 0.f){ invr = dr/den; invi = -di/den; }
    #pragma unroll
    for (int rep=0; rep<2; ++rep){
      int c = tid + rep*256;
      float vr_=vre[c], vi_=vim[c], qr_=qre[c], qi_=qim[c];
      float dxr = vr_-mxr, dxi = vi_-mxi;
      float dyr = qr_-myr, dyi = qi_-myi;
      float cvr = dxr*dyr - dxi*dyi;
      float cvi = dxr*dyi + dxi*dyr;
      float rr = cvr*invr - cvi*invi;
      float ri = cvr*invi + cvi*invr;
      float ang = atan2f(ri, rr + 1.0e-4f);
      float wm = tanhf(ang*0.25f);           // 2*sigmoid(2x)-1 == tanh(x), x=ang*0.25
      if (!(wm==wm)) wm = 0.f;
      float fdr = vr_-qr_, fdi = vi_-qi_;
      float w = expf(-0.5f*(fdr*fdr+fdi*fdi))*wm;
      vre[c] = qr_ + w*fdr;                  // qf*(1-w)+vf*w
      vim[c] = qi_ + w*fdi;
    }
    fft512(vre,vim,twr,twi,-1.0f,tid);       // unscaled inverse
    size_t base = ((size_t)((b*KN+k)*2048 + l))*512;
    for (int c=tid;c<512;c+=256){
      float mag = sqrtf(vre[c]*vre[c]+vim[c]*vim[c])*(1.0f/512.0f);
      outs[base+c] = f2bf(mag);
    }
  }
}

// scores[b,c,k] = sum_l qmean[b,l] * outs[b,k,l,c]
__global__ __launch_bounds__(256) void scores_kernel(
    const unsigned short* __restrict__ outs, const float* __restrict__ qmean,
    float* __restrict__ scores)
{
  int tid = threadIdx.x;
  int l0 = blockIdx.x*128;
  int k = blockIdx.y;
  int b = blockIdx.z;
  int c = tid*2;
  float accx=0.f, accy=0.f;
  for (int l=l0; l<l0+128; ++l){
    float s = qmean[b*2048+l];
    const unsigned short* p = outs + ((size_t)((b*KN+k)*2048 + l))*512 + c;
    unsigned int u = *(const unsigned int*)p;
    accx += s*bf2f((unsigned short)(u&0xffffu));
    accy += s*bf2f((unsigned short)(u>>16));
  }
  atomicAdd(&scores[(size_t)(b*512+c)*KN + k], accx);
  atomicAdd(&scores[(size_t)(b*512+c+1)*KN + k], accy);
}

// out[b,c,l] = sum_k softmax_k(scores[b,c,:]) * outs[b,k,l,c]
__global__ __launch_bounds__(256) void combine_kernel(
    const unsigned short* __restrict__ outs, const float* __restrict__ scores,
    float* __restrict__ out)
{
  __shared__ float wa[64][KN];
  int cx = threadIdx.x;      // 64
  int ly = threadIdx.y;      // 4
  int l0 = blockIdx.x*64;
  int c  = blockIdx.y*64 + cx;
  int b  = blockIdx.z;
  if (ly==0){
    float4 s = *reinterpret_cast<const float4*>(&scores[(size_t)(b*512+c)*KN]);
    float m = fmaxf(fmaxf(s.x,s.y),fmaxf(s.z,s.w));
    float e0=expf(s.x-m), e1=expf(s.y-m), e2=expf(s.z-m), e3=expf(s.w-m);
    float inv = 1.f/(e0+e1+e2+e3);
    wa[cx][0]=e0*inv; wa[cx][1]=e1*inv; wa[cx][2]=e2*inv; wa[cx][3]=e3*inv;
  }
  __syncthreads();
  float acc[16];
  #pragma unroll
  for (int i=0;i<16;++i) acc[i]=0.f;
  for (int k=0;k<KN;++k){
    float w = wa[cx][k];
    const unsigned short* p = outs + ((size_t)((b*KN+k)*2048) + l0 + ly*16)*512 + c;
    #pragma unroll
    for (int i=0;i<16;++i){
      acc[i] += w*bf2f(p[(size_t)i*512]);
    }
  }
  float* op = out + ((size_t)(b*512+c))*2048 + l0 + ly*16;
  #pragma unroll
  for (int i=0;i<16;i+=4){
    float4 v = make_float4(acc[i],acc[i+1],acc[i+2],acc[i+3]);
    *reinterpret_cast<float4*>(op+i) = v;
  }
}

extern "C" void kernel_launch(void* const* d_in, const int* in_sizes, int n_in,
                              void* d_out, int out_size, void* d_ws, size_t ws_size,
                              hipStream_t stream)
{
  const float* x   = (const float*)d_in[0];
  const float* q   = (const float*)d_in[1];
  const float* sig = (const float*)d_in[2];
  const float* cen = (const float*)d_in[3];
  const int*   ksp = (const int*)d_in[4];
  float* out = (float*)d_out;

  // workspace layout: outs (bf16, B*KN*L*C) | qmean (f32, B*L) | scores (f32, B*C*KN)
  unsigned short* outs = (unsigned short*)d_ws;
  size_t outs_elems = (size_t)B_DIM*KN*L_DIM*C_DIM;
  float* qmeanb = (float*)((char*)d_ws + outs_elems*sizeof(unsigned short));
  float* scores = qmeanb + (size_t)B_DIM*L_DIM;

  hipMemsetAsync(scores, 0, (size_t)B_DIM*C_DIM*KN*sizeof(float), stream);

  dim3 g1(L_DIM, B_DIM);
  hipLaunchKernelGGL(col_kernel, g1, dim3(256), 0, stream,
                     x, q, sig, cen, ksp, outs, qmeanb);
  dim3 g2(L_DIM/128, KN, B_DIM);
  hipLaunchKernelGGL(scores_kernel, g2, dim3(256), 0, stream, outs, qmeanb, scores);
  dim3 g3(L_DIM/64, C_DIM/64, B_DIM);
  hipLaunchKernelGGL(combine_kernel, g3, dim3(64,4), 0, stream, outs, scores, out);
}

// Round 2
// 276.892 us; speedup vs baseline: 1.4438x; 1.4438x over previous
//
#include <hip/hip_runtime.h>
#include <hip/hip_bf16.h>

#define B_DIM 4
#define C_DIM 512
#define L_DIM 2048
#define KN 4
#define MAXKS 9

__device__ inline float bf2f(unsigned short u){ return __uint_as_float(((unsigned)u)<<16); }
__device__ inline unsigned short f2bf(float f){
  unsigned u = __float_as_uint(f);
  unsigned r = (u + 0x7fffu + ((u>>16)&1u))>>16;
  return (unsigned short)r;
}

// ---------- wave-level 512-pt FFT: 64 lanes x 8 regs ----------
// layout fwd-in : lane l, slot j holds x[8*l + j]           (natural, contiguous per lane)
// layout freq   : lane l, slot k2 holds X[rev6(l) + 64*k2]
// fwd: 6-stage DIF across lanes -> twiddle W512^(-n2*k1) -> 8-pt reg FFT
// inv: 8-pt reg iFFT -> conj twiddle -> 6-stage DIT across lanes (unscaled; /512 at end)

__device__ __forceinline__ void lane_fft_fwd(float* zr, float* zi,
                                             const float* stw_r, const float* stw_i, int lane){
  #pragma unroll
  for (int s=5; s>=0; --s){
    int m = 1<<s;
    bool hi = (lane & m) != 0;
    float wr = stw_r[s], wi = stw_i[s];
    #pragma unroll
    for (int j=0;j<8;++j){
      float pr = __shfl_xor(zr[j], m);
      float pi = __shfl_xor(zi[j], m);
      float sr = hi ? (pr - zr[j]) : (zr[j] + pr);
      float si = hi ? (pi - zi[j]) : (zi[j] + pi);
      float mr = sr*wr - si*wi;
      float mi = sr*wi + si*wr;
      zr[j] = hi ? mr : sr;
      zi[j] = hi ? mi : si;
    }
  }
}

__device__ __forceinline__ void lane_fft_inv(float* zr, float* zi,
                                             const float* stw_r, const float* stw_i, int lane){
  #pragma unroll
  for (int s=0; s<6; ++s){
    int m = 1<<s;
    bool hi = (lane & m) != 0;
    float wr = stw_r[s], wi = -stw_i[s];   // conjugate of forward stage twiddle
    #pragma unroll
    for (int j=0;j<8;++j){
      float pr = __shfl_xor(zr[j], m);
      float pi = __shfl_xor(zi[j], m);
      float ar = hi ? zr[j] : pr;          // the "odd" operand gets the twiddle
      float ai = hi ? zi[j] : pi;
      float mr = ar*wr - ai*wi;
      float mi = ar*wi + ai*wr;
      zr[j] = hi ? (pr - mr) : (zr[j] + mr);
      zi[j] = hi ? (pi - mi) : (zi[j] + mi);
    }
  }
}

__device__ __forceinline__ void fft8_reg(float* zr, float* zi, float sgn){
  // sgn = -1 forward, +1 inverse (unscaled)
  const float C = 0.70710678118654752f;
  float s0r=zr[0]+zr[4], s0i=zi[0]+zi[4];
  float s1r=zr[0]-zr[4], s1i=zi[0]-zi[4];
  float s2r=zr[2]+zr[6], s2i=zi[2]+zi[6];
  float s3r=zr[2]-zr[6], s3i=zi[2]-zi[6];
  float e0r=s0r+s2r, e0i=s0i+s2i;
  float e2r=s0r-s2r, e2i=s0i-s2i;
  float j3r=-sgn*s3i, j3i=sgn*s3r;
  float e1r=s1r+j3r, e1i=s1i+j3i;
  float e3r=s1r-j3r, e3i=s1i-j3i;
  float t0r=zr[1]+zr[5], t0i=zi[1]+zi[5];
  float t1r=zr[1]-zr[5], t1i=zi[1]-zi[5];
  float t2r=zr[3]+zr[7], t2i=zi[3]+zi[7];
  float t3r=zr[3]-zr[7], t3i=zi[3]-zi[7];
  float o0r=t0r+t2r, o0i=t0i+t2i;
  float o2r=t0r-t2r, o2i=t0i-t2i;
  float k3r=-sgn*t3i, k3i=sgn*t3r;
  float o1r=t1r+k3r, o1i=t1i+k3i;
  float o3r=t1r-k3r, o3i=t1i-k3i;
  float w1o_r = C*o1r - sgn*C*o1i;
  float w1o_i = C*o1i + sgn*C*o1r;
  float w2o_r = -sgn*o2i, w2o_i = sgn*o2r;
  float w3o_r = -C*o3r - sgn*C*o3i;
  float w3o_i = -C*o3i + sgn*C*o3r;
  zr[0]=e0r+o0r;   zi[0]=e0i+o0i;
  zr[4]=e0r-o0r;   zi[4]=e0i-o0i;
  zr[1]=e1r+w1o_r; zi[1]=e1i+w1o_i;
  zr[5]=e1r-w1o_r; zi[5]=e1i-w1o_i;
  zr[2]=e2r+w2o_r; zi[2]=e2i+w2o_i;
  zr[6]=e2r-w2o_r; zi[6]=e2i-w2o_i;
  zr[3]=e3r+w3o_r; zi[3]=e3i+w3o_i;
  zr[7]=e3r-w3o_r; zi[7]=e3i-w3o_i;
}

__device__ __forceinline__ void fft512_fwd(float* zr, float* zi,
    const float* stw_r, const float* stw_i,
    const float* btw_r, const float* btw_i, int lane){
  lane_fft_fwd(zr, zi, stw_r, stw_i, lane);
  #pragma unroll
  for (int j=1;j<8;++j){
    float ar=zr[j], ai=zi[j];
    zr[j]=ar*btw_r[j]-ai*btw_i[j];
    zi[j]=ar*btw_i[j]+ai*btw_r[j];
  }
  fft8_reg(zr, zi, -1.f);
}

__device__ __forceinline__ void fft512_inv(float* zr, float* zi,
    const float* stw_r, const float* stw_i,
    const float* btw_r, const float* btw_i, int lane){
  fft8_reg(zr, zi, +1.f);
  #pragma unroll
  for (int j=1;j<8;++j){
    float ar=zr[j], ai=zi[j];
    zr[j]= ar*btw_r[j]+ai*btw_i[j];     // multiply by conj(btw)
    zi[j]=-ar*btw_i[j]+ai*btw_r[j];
  }
  lane_fft_inv(zr, zi, stw_r, stw_i, lane);
}

__device__ __forceinline__ void wreduce4(float&a,float&b,float&c,float&d){
  #pragma unroll
  for (int off=1; off<64; off<<=1){
    a += __shfl_xor(a,off); b += __shfl_xor(b,off);
    c += __shfl_xor(c,off); d += __shfl_xor(d,off);
  }
}

__global__ __launch_bounds__(256) void col_kernel(
    const float* __restrict__ x, const float* __restrict__ q,
    const float* __restrict__ sigmas, const float* __restrict__ centers,
    const int* __restrict__ ksp,
    unsigned short* __restrict__ outs, float* __restrict__ qmean)
{
  __shared__ float kern[KN][MAXKS];
  int tid  = threadIdx.x;
  int wave = tid >> 6;
  int lane = tid & 63;
  int col  = blockIdx.x*4 + wave;          // col = b*2048 + l
  int b = col >> 11;
  int l = col & 2047;
  int ks  = ksp[0];
  int pad = ks >> 1;

  if (tid < KN){                            // gaussian taps, normalized (two-pass, no scratch)
    float half = 0.5f*(float)(ks-1);
    float sg = sigmas[tid] + 0.001f;
    float ce = centers[tid];
    float s = 0.f;
    for (int t=0;t<ks;++t){ float d=((float)t-half-ce)/sg; s += expf(-0.5f*d*d); }
    float inv = 1.f/(s+0.01f);
    for (int t=0;t<ks;++t){ float d=((float)t-half-ce)/sg; kern[tid][t] = expf(-0.5f*d*d)*inv; }
  }
  __syncthreads();

  const float PI = 3.14159265358979323846f;
  int k1 = (int)(__brev((unsigned)lane) >> 26);   // this lane's bin-low index after lane FFT

  float stw_r[6], stw_i[6];                 // stage twiddles W_{2m}^{-(lane&(m-1))}
  #pragma unroll
  for (int s=0; s<6; ++s){
    int m = 1<<s;
    float ang = -PI * (float)(lane & (m-1)) / (float)m;
    float sn, cs; sincosf(ang, &sn, &cs);
    stw_r[s]=cs; stw_i[s]=sn;
  }
  float btw_r[8], btw_i[8];                 // W512^{-j*k1}
  #pragma unroll
  for (int j=0;j<8;++j){
    float ang = -2.f*PI*(float)(j*k1)/512.f;
    float sn, cs; sincosf(ang, &sn, &cs);
    btw_r[j]=cs; btw_i[j]=sn;
  }

  // ---- load q column (8 channels per lane) + conv x columns into registers ----
  float qre[8], qim[8];
  const float* qbase = q + ((size_t)(b*512) + lane*8)*2048 + l;
  #pragma unroll
  for (int j=0;j<8;++j){ qre[j] = qbase[(size_t)j*2048]; qim[j]=0.f; }

  float cv[KN][8];
  #pragma unroll
  for (int k=0;k<KN;++k){
    #pragma unroll
    for (int j=0;j<8;++j) cv[k][j]=0.f;
  }
  const float* xbase = x + ((size_t)(b*512) + lane*8)*2048;
  for (int t=0;t<ks;++t){
    int li = l + t - pad;
    li = li<0 ? 0 : (li>2047 ? 2047 : li);
    float xv[8];
    #pragma unroll
    for (int j=0;j<8;++j) xv[j] = xbase[(size_t)j*2048 + li];
    #pragma unroll
    for (int k=0;k<KN;++k){
      float w = kern[k][t];
      #pragma unroll
      for (int j=0;j<8;++j) cv[k][j] += w*xv[j];
    }
  }

  // ---- q forward FFT + stats ----
  fft512_fwd(qre,qim,stw_r,stw_i,btw_r,btw_i,lane);
  if (lane==0) qmean[b*2048+l] = qre[0]*(1.f/512.f);   // bin0 = sum(q)

  float S1r=0.f,S1i=0.f,S2r=0.f,S2i=0.f;
  #pragma unroll
  for (int j=0;j<8;++j){
    S1r += qre[j]; S1i += qim[j];
    S2r += qre[j]*qre[j]-qim[j]*qim[j];
    S2i += 2.f*qre[j]*qim[j];
  }
  wreduce4(S1r,S1i,S2r,S2i);
  float myr = S1r*(1.f/512.f), myi = S1i*(1.f/512.f);
  float bsr = S2r - (S1r*myr - S1i*myi);
  float bsi = S2i - (S1r*myi + S1i*myr);

  // ---- per gaussian kernel: FFT, correlate, filter, iFFT, store ----
  #pragma unroll
  for (int k=0;k<KN;++k){
    float vr[8], vi[8];
    #pragma unroll
    for (int j=0;j<8;++j){ vr[j]=cv[k][j]; vi[j]=0.f; }
    fft512_fwd(vr,vi,stw_r,stw_i,btw_r,btw_i,lane);

    float T1r=0.f,T1i=0.f,T2r=0.f,T2i=0.f;
    #pragma unroll
    for (int j=0;j<8;++j){
      T1r += vr[j]; T1i += vi[j];
      T2r += vr[j]*vr[j]-vi[j]*vi[j];
      T2i += 2.f*vr[j]*vi[j];
    }
    wreduce4(T1r,T1i,T2r,T2i);
    float mxr = T1r*(1.f/512.f), mxi = T1i*(1.f/512.f);
    float asr = T2r - (T1r*mxr - T1i*mxi);
    float asi = T2i - (T1r*mxi + T1i*mxr);
    // inv = conj(csqrt(a*b + 1e-4)) / |csqrt|^2
    float zr_ = asr*bsr - asi*bsi + 1.0e-4f;
    float zi_ = asr*bsi + asi*bsr;
    float rmag = sqrtf(zr_*zr_+zi_*zi_);
    float dr = sqrtf(fmaxf(0.5f*(rmag+zr_),0.f));
    float di = sqrtf(fmaxf(0.5f*(rmag-zr_),0.f));
    di = (zi_ < 0.f) ? -di : di;
    float den = dr*dr + di*di;
    float invr = 0.f, invi = 0.f;
    if (den > 0.f){ invr = dr/den; invi = -di/den; }

    #pragma unroll
    for (int j=0;j<8;++j){
      float vr_=vr[j], vi_=vi[j], qr_=qre[j], qi_=qim[j];
      float dxr = vr_-mxr, dxi = vi_-mxi;
      float dyr = qr_-myr, dyi = qi_-myi;
      float cvr = dxr*dyr - dxi*dyi;
      float cvi = dxr*dyi + dxi*dyr;
      float rr = cvr*invr - cvi*invi;
      float ri = cvr*invi + cvi*invr;
      float ang = atan2f(ri, rr + 1.0e-4f);
      float wm  = tanhf(ang*0.25f);          // 2*sigmoid(2x)-1 == tanh(x)
      if (!(wm==wm)) wm = 0.f;
      float fdr = vr_-qr_, fdi = vi_-qi_;
      float w = expf(-0.5f*(fdr*fdr+fdi*fdi))*wm;
      vr[j] = qr_ + w*fdr;                   // qf*(1-w)+vf*w
      vi[j] = qi_ + w*fdi;
    }

    fft512_inv(vr,vi,stw_r,stw_i,btw_r,btw_i,lane);

    size_t obase = ((size_t)((b*KN+k)*2048 + l))*512 + lane*8;
    unsigned short ob[8];
    #pragma unroll
    for (int j=0;j<8;++j){
      float mag = sqrtf(vr[j]*vr[j]+vi[j]*vi[j])*(1.f/512.f);
      ob[j] = f2bf(mag);
    }
    uint4 pk;
    pk.x = (unsigned)ob[0] | ((unsigned)ob[1]<<16);
    pk.y = (unsigned)ob[2] | ((unsigned)ob[3]<<16);
    pk.z = (unsigned)ob[4] | ((unsigned)ob[5]<<16);
    pk.w = (unsigned)ob[6] | ((unsigned)ob[7]<<16);
    *reinterpret_cast<uint4*>(outs + obase) = pk;
  }
}

// scores[b,c,k] = sum_l qmean[b,l] * outs[b,k,l,c]
__global__ __launch_bounds__(256) void scores_kernel(
    const unsigned short* __restrict__ outs, const float* __restrict__ qmean,
    float* __restrict__ scores)
{
  int tid = threadIdx.x;
  int l0 = blockIdx.x*128;
  int k = blockIdx.y;
  int b = blockIdx.z;
  int c = tid*2;
  float accx=0.f, accy=0.f;
  for (int l=l0; l<l0+128; ++l){
    float s = qmean[b*2048+l];
    const unsigned short* p = outs + ((size_t)((b*KN+k)*2048 + l))*512 + c;
    unsigned int u = *(const unsigned int*)p;
    accx += s*bf2f((unsigned short)(u&0xffffu));
    accy += s*bf2f((unsigned short)(u>>16));
  }
  atomicAdd(&scores[(size_t)(b*512+c)*KN + k], accx);
  atomicAdd(&scores[(size_t)(b*512+c+1)*KN + k], accy);
}

// out[b,c,l] = sum_k softmax_k(scores[b,c,:]) * outs[b,k,l,c]
__global__ __launch_bounds__(256) void combine_kernel(
    const unsigned short* __restrict__ outs, const float* __restrict__ scores,
    float* __restrict__ out)
{
  __shared__ float wa[64][KN];
  int cx = threadIdx.x;      // 64
  int ly = threadIdx.y;      // 4
  int l0 = blockIdx.x*64;
  int c  = blockIdx.y*64 + cx;
  int b  = blockIdx.z;
  if (ly==0){
    float4 s = *reinterpret_cast<const float4*>(&scores[(size_t)(b*512+c)*KN]);
    float m = fmaxf(fmaxf(s.x,s.y),fmaxf(s.z,s.w));
    float e0=expf(s.x-m), e1=expf(s.y-m), e2=expf(s.z-m), e3=expf(s.w-m);
    float inv = 1.f/(e0+e1+e2+e3);
    wa[cx][0]=e0*inv; wa[cx][1]=e1*inv; wa[cx][2]=e2*inv; wa[cx][3]=e3*inv;
  }
  __syncthreads();
  float acc[16];
  #pragma unroll
  for (int i=0;i<16;++i) acc[i]=0.f;
  for (int k=0;k<KN;++k){
    float w = wa[cx][k];
    const unsigned short* p = outs + ((size_t)((b*KN+k)*2048) + l0 + ly*16)*512 + c;
    #pragma unroll
    for (int i=0;i<16;++i){
      acc[i] += w*bf2f(p[(size_t)i*512]);
    }
  }
  float* op = out + ((size_t)(b*512+c))*2048 + l0 + ly*16;
  #pragma unroll
  for (int i=0;i<16;i+=4){
    float4 v = make_float4(acc[i],acc[i+1],acc[i+2],acc[i+3]);
    *reinterpret_cast<float4*>(op+i) = v;
  }
}

extern "C" void kernel_launch(void* const* d_in, const int* in_sizes, int n_in,
                              void* d_out, int out_size, void* d_ws, size_t ws_size,
                              hipStream_t stream)
{
  const float* x   = (const float*)d_in[0];
  const float* q   = (const float*)d_in[1];
  const float* sig = (const float*)d_in[2];
  const float* cen = (const float*)d_in[3];
  const int*   ksp = (const int*)d_in[4];
  float* out = (float*)d_out;

  // workspace: outs (bf16, B*KN*L*C) | qmean (f32, B*L) | scores (f32, B*C*KN)
  unsigned short* outs = (unsigned short*)d_ws;
  size_t outs_elems = (size_t)B_DIM*KN*L_DIM*C_DIM;
  float* qmeanb = (float*)((char*)d_ws + outs_elems*sizeof(unsigned short));
  float* scores = qmeanb + (size_t)B_DIM*L_DIM;

  hipMemsetAsync(scores, 0, (size_t)B_DIM*C_DIM*KN*sizeof(float), stream);

  dim3 g1(B_DIM*L_DIM/4);
  hipLaunchKernelGGL(col_kernel, g1, dim3(256), 0, stream,
                     x, q, sig, cen, ksp, outs, qmeanb);
  dim3 g2(L_DIM/128, KN, B_DIM);
  hipLaunchKernelGGL(scores_kernel, g2, dim3(256), 0, stream, outs, qmeanb, scores);
  dim3 g3(L_DIM/64, C_DIM/64, B_DIM);
  hipLaunchKernelGGL(combine_kernel, g3, dim3(64,4), 0, stream, outs, scores, out);
}

// Round 3
// 250.176 us; speedup vs baseline: 1.5980x; 1.1068x over previous
//
#include <hip/hip_runtime.h>
#include <hip/hip_bf16.h>

#define B_DIM 4
#define C_DIM 512
#define L_DIM 2048
#define KN 4
#define MAXKS 9

__device__ inline float bf2f(unsigned short u){ return __uint_as_float(((unsigned)u)<<16); }
__device__ inline unsigned short f2bf(float f){
  unsigned u = __float_as_uint(f);
  unsigned r = (u + 0x7fffu + ((u>>16)&1u))>>16;
  return (unsigned short)r;
}

// branchless atan2, ~1e-5 rad abs error
__device__ __forceinline__ float fast_atan2(float y, float x){
  float ax = fabsf(x), ay = fabsf(y);
  float mx = fmaxf(ax, ay), mn = fminf(ax, ay);
  float t = __fdividef(mn, mx);                 // mx==0 -> NaN -> caught by wm guard
  float a = t*t;
  float r = t*(0.9998660f + a*(-0.3302995f + a*(0.1801410f + a*(-0.0851330f + a*0.0208351f))));
  r = (ay > ax) ? 1.5707963267948966f - r : r;
  r = (x < 0.f) ? 3.14159265358979323846f - r : r;
  return copysignf(r, y);
}
// tanh(u) = (e^{2u}-1)/(e^{2u}+1), one native v_exp
__device__ __forceinline__ float fast_tanh(float u){
  float e = exp2f(2.8853900817779268f*u);       // e^{2u}
  return __fdividef(e-1.f, e+1.f);
}

// ---------- wave-level 512-pt FFT: 64 lanes x 8 regs ----------
// time layout : lane l, slot j holds x[8*l + j]
// freq layout : lane l, slot j holds X[rev6(l) + 64*j]
__device__ __forceinline__ void lane_fft_fwd(float* zr, float* zi,
                                             const float* stw_r, const float* stw_i, int lane){
  #pragma unroll
  for (int s=5; s>=0; --s){
    int m = 1<<s;
    bool hi = (lane & m) != 0;
    float wr = stw_r[s], wi = stw_i[s];
    #pragma unroll
    for (int j=0;j<8;++j){
      float pr = __shfl_xor(zr[j], m);
      float pi = __shfl_xor(zi[j], m);
      float sr = hi ? (pr - zr[j]) : (zr[j] + pr);
      float si = hi ? (pi - zi[j]) : (zi[j] + pi);
      float mr = sr*wr - si*wi;
      float mi = sr*wi + si*wr;
      zr[j] = hi ? mr : sr;
      zi[j] = hi ? mi : si;
    }
  }
}

__device__ __forceinline__ void lane_fft_inv(float* zr, float* zi,
                                             const float* stw_r, const float* stw_i, int lane){
  #pragma unroll
  for (int s=0; s<6; ++s){
    int m = 1<<s;
    bool hi = (lane & m) != 0;
    float wr = stw_r[s], wi = -stw_i[s];
    #pragma unroll
    for (int j=0;j<8;++j){
      float pr = __shfl_xor(zr[j], m);
      float pi = __shfl_xor(zi[j], m);
      float ar = hi ? zr[j] : pr;
      float ai = hi ? zi[j] : pi;
      float mr = ar*wr - ai*wi;
      float mi = ar*wi + ai*wr;
      zr[j] = hi ? (pr - mr) : (zr[j] + mr);
      zi[j] = hi ? (pi - mi) : (zi[j] + mi);
    }
  }
}

__device__ __forceinline__ void fft8_reg(float* zr, float* zi, float sgn){
  const float C = 0.70710678118654752f;
  float s0r=zr[0]+zr[4], s0i=zi[0]+zi[4];
  float s1r=zr[0]-zr[4], s1i=zi[0]-zi[4];
  float s2r=zr[2]+zr[6], s2i=zi[2]+zi[6];
  float s3r=zr[2]-zr[6], s3i=zi[2]-zi[6];
  float e0r=s0r+s2r, e0i=s0i+s2i;
  float e2r=s0r-s2r, e2i=s0i-s2i;
  float j3r=-sgn*s3i, j3i=sgn*s3r;
  float e1r=s1r+j3r, e1i=s1i+j3i;
  float e3r=s1r-j3r, e3i=s1i-j3i;
  float t0r=zr[1]+zr[5], t0i=zi[1]+zi[5];
  float t1r=zr[1]-zr[5], t1i=zi[1]-zi[5];
  float t2r=zr[3]+zr[7], t2i=zi[3]+zi[7];
  float t3r=zr[3]-zr[7], t3i=zi[3]-zi[7];
  float o0r=t0r+t2r, o0i=t0i+t2i;
  float o2r=t0r-t2r, o2i=t0i-t2i;
  float k3r=-sgn*t3i, k3i=sgn*t3r;
  float o1r=t1r+k3r, o1i=t1i+k3i;
  float o3r=t1r-k3r, o3i=t1i-k3i;
  float w1o_r = C*o1r - sgn*C*o1i;
  float w1o_i = C*o1i + sgn*C*o1r;
  float w2o_r = -sgn*o2i, w2o_i = sgn*o2r;
  float w3o_r = -C*o3r - sgn*C*o3i;
  float w3o_i = -C*o3i + sgn*C*o3r;
  zr[0]=e0r+o0r;   zi[0]=e0i+o0i;
  zr[4]=e0r-o0r;   zi[4]=e0i-o0i;
  zr[1]=e1r+w1o_r; zi[1]=e1i+w1o_i;
  zr[5]=e1r-w1o_r; zi[5]=e1i-w1o_i;
  zr[2]=e2r+w2o_r; zi[2]=e2i+w2o_i;
  zr[6]=e2r-w2o_r; zi[6]=e2i-w2o_i;
  zr[3]=e3r+w3o_r; zi[3]=e3i+w3o_i;
  zr[7]=e3r-w3o_r; zi[7]=e3i-w3o_i;
}

__device__ __forceinline__ void fft512_fwd(float* zr, float* zi,
    const float* stw_r, const float* stw_i,
    const float* btw_r, const float* btw_i, int lane){
  lane_fft_fwd(zr, zi, stw_r, stw_i, lane);
  #pragma unroll
  for (int j=1;j<8;++j){
    float ar=zr[j], ai=zi[j];
    zr[j]=ar*btw_r[j]-ai*btw_i[j];
    zi[j]=ar*btw_i[j]+ai*btw_r[j];
  }
  fft8_reg(zr, zi, -1.f);
}

__device__ __forceinline__ void fft512_inv(float* zr, float* zi,
    const float* stw_r, const float* stw_i,
    const float* btw_r, const float* btw_i, int lane){
  fft8_reg(zr, zi, +1.f);
  #pragma unroll
  for (int j=1;j<8;++j){
    float ar=zr[j], ai=zi[j];
    zr[j]= ar*btw_r[j]+ai*btw_i[j];
    zi[j]=-ar*btw_i[j]+ai*btw_r[j];
  }
  lane_fft_inv(zr, zi, stw_r, stw_i, lane);
}

// Unpack two real-signal spectra from one packed complex FFT.
// A[k]=(Z[k]+conj(Z[N-k]))/2 ; B[k]=(Z[k]-conj(Z[N-k]))/(2i)
// bin(lane,j)=rev6(lane)+64j ; partner at lane plane, slot 7-j (lane0: self, slot (8-j)&7)
__device__ __forceinline__ void rfft_separate(const float* zr, const float* zi,
    float* ar, float* ai, float* br, float* bi, int plane, int lane){
  #pragma unroll
  for (int j=0;j<8;++j){
    const int js = 7-j;
    const int j0 = (8-j)&7;
    float pr = __shfl(zr[js], plane);
    float pi = __shfl(zi[js], plane);
    pr = (lane==0) ? zr[j0] : pr;
    pi = (lane==0) ? zi[j0] : pi;
    ar[j] = 0.5f*(zr[j]+pr);
    ai[j] = 0.5f*(zi[j]-pi);
    br[j] = 0.5f*(zi[j]+pi);
    bi[j] = 0.5f*(pr-zr[j]);
  }
}

__device__ __forceinline__ void wreduce4(float&a,float&b,float&c,float&d){
  #pragma unroll
  for (int off=1; off<64; off<<=1){
    a += __shfl_xor(a,off); b += __shfl_xor(b,off);
    c += __shfl_xor(c,off); d += __shfl_xor(d,off);
  }
}

// stats -> correlation weight -> filter -> iFFT -> bf16 store (in place on vr/vi)
__device__ __forceinline__ void process_k(float* vr, float* vi,
    const float* qre, const float* qim,
    float myr, float myi, float bsr, float bsi,
    const float* stw_r, const float* stw_i,
    const float* btw_r, const float* btw_i,
    int lane, unsigned short* outp)
{
  float T1r=0.f,T1i=0.f,T2r=0.f,T2i=0.f;
  #pragma unroll
  for (int j=0;j<8;++j){
    T1r += vr[j]; T1i += vi[j];
    T2r += vr[j]*vr[j]-vi[j]*vi[j];
    T2i += 2.f*vr[j]*vi[j];
  }
  wreduce4(T1r,T1i,T2r,T2i);
  float mxr = T1r*(1.f/512.f), mxi = T1i*(1.f/512.f);
  float asr = T2r - (T1r*mxr - T1i*mxi);
  float asi = T2i - (T1r*mxi + T1i*mxr);
  float zr_ = asr*bsr - asi*bsi + 1.0e-4f;
  float zi_ = asr*bsi + asi*bsr;
  float rmag = sqrtf(zr_*zr_+zi_*zi_);
  float dr = sqrtf(fmaxf(0.5f*(rmag+zr_),0.f));
  float di = sqrtf(fmaxf(0.5f*(rmag-zr_),0.f));
  di = (zi_ < 0.f) ? -di : di;
  float den = dr*dr + di*di;
  float invden = __fdividef(1.f, den);
  float invr = (den>0.f) ? dr*invden : 0.f;
  float invi = (den>0.f) ? -di*invden : 0.f;

  #pragma unroll
  for (int j=0;j<8;++j){
    float vr_=vr[j], vi_=vi[j], qr_=qre[j], qi_=qim[j];
    float dxr = vr_-mxr, dxi = vi_-mxi;
    float dyr = qr_-myr, dyi = qi_-myi;
    float cvr = dxr*dyr - dxi*dyi;
    float cvi = dxr*dyi + dxi*dyr;
    float rr = cvr*invr - cvi*invi;
    float ri = cvr*invi + cvi*invr;
    float ang = fast_atan2(ri, rr + 1.0e-4f);
    float wm  = fast_tanh(ang*0.25f);
    if (!(wm==wm)) wm = 0.f;
    float fdr = vr_-qr_, fdi = vi_-qi_;
    float fd2 = fdr*fdr+fdi*fdi;
    float w = exp2f(-0.72134752044448170f*fd2)*wm;   // exp(-0.5*fd2)
    vr[j] = qr_ + w*fdr;
    vi[j] = qi_ + w*fdi;
  }

  fft512_inv(vr,vi,stw_r,stw_i,btw_r,btw_i,lane);

  unsigned short ob[8];
  #pragma unroll
  for (int j=0;j<8;++j){
    float mag = sqrtf(vr[j]*vr[j]+vi[j]*vi[j])*(1.f/512.f);
    ob[j] = f2bf(mag);
  }
  uint4 pk;
  pk.x = (unsigned)ob[0] | ((unsigned)ob[1]<<16);
  pk.y = (unsigned)ob[2] | ((unsigned)ob[3]<<16);
  pk.z = (unsigned)ob[4] | ((unsigned)ob[5]<<16);
  pk.w = (unsigned)ob[6] | ((unsigned)ob[7]<<16);
  *reinterpret_cast<uint4*>(outp) = pk;
}

__global__ __launch_bounds__(256,3) void col_kernel(
    const float* __restrict__ x, const float* __restrict__ q,
    const float* __restrict__ sigmas, const float* __restrict__ centers,
    const int* __restrict__ ksp,
    unsigned short* __restrict__ outs, float* __restrict__ qmean)
{
  __shared__ float kern[KN][MAXKS];
  int tid  = threadIdx.x;
  int wave = tid >> 6;
  int lane = tid & 63;
  int col  = blockIdx.x*4 + wave;          // col = b*2048 + l
  int b = col >> 11;
  int l = col & 2047;
  int ks  = ksp[0];
  int pad = ks >> 1;

  if (tid < KN){
    float half = 0.5f*(float)(ks-1);
    float sg = sigmas[tid] + 0.001f;
    float ce = centers[tid];
    float s = 0.f;
    for (int t=0;t<ks;++t){ float d=((float)t-half-ce)/sg; s += expf(-0.5f*d*d); }
    float inv = 1.f/(s+0.01f);
    for (int t=0;t<ks;++t){ float d=((float)t-half-ce)/sg; kern[tid][t] = expf(-0.5f*d*d)*inv; }
  }
  __syncthreads();

  const float PI = 3.14159265358979323846f;
  int k1 = (int)(__brev((unsigned)lane) >> 26);
  int plane; { int pk_ = (64-k1)&63; plane = (int)(__brev((unsigned)pk_)>>26); }

  float stw_r[6], stw_i[6];
  #pragma unroll
  for (int s=0; s<6; ++s){
    int m = 1<<s;
    float ang = -PI * (float)(lane & (m-1)) / (float)m;
    stw_r[s]=__cosf(ang); stw_i[s]=__sinf(ang);
  }
  float btw_r[8], btw_i[8];
  #pragma unroll
  for (int j=0;j<8;++j){
    float ang = -2.f*PI*(float)(j*k1)/512.f;
    btw_r[j]=__cosf(ang); btw_i[j]=__sinf(ang);
  }

  // ---- load q column + conv accumulators (all real) ----
  float qv[8];
  const float* qbase = q + ((size_t)(b*512) + lane*8)*2048 + l;
  #pragma unroll
  for (int j=0;j<8;++j) qv[j] = qbase[(size_t)j*2048];

  float c0[8], c1[8], c2[8], c3[8];
  #pragma unroll
  for (int j=0;j<8;++j){ c0[j]=0.f; c1[j]=0.f; c2[j]=0.f; c3[j]=0.f; }
  const float* xbase = x + ((size_t)(b*512) + lane*8)*2048;
  for (int t=0;t<ks;++t){
    int li = l + t - pad;
    li = li<0 ? 0 : (li>2047 ? 2047 : li);
    float w0=kern[0][t], w1=kern[1][t], w2=kern[2][t], w3=kern[3][t];
    #pragma unroll
    for (int j=0;j<8;++j){
      float xv = xbase[(size_t)j*2048 + li];
      c0[j] += w0*xv; c1[j] += w1*xv; c2[j] += w2*xv; c3[j] += w3*xv;
    }
  }

  // ---- packed FFT P1: q + i*c0 ----
  fft512_fwd(qv, c0, stw_r,stw_i,btw_r,btw_i, lane);
  float qre[8], qim[8], vr[8], vi[8];
  rfft_separate(qv, c0, qre, qim, vr, vi, plane, lane);

  if (lane==0) qmean[b*2048+l] = qre[0]*(1.f/512.f);

  float S1r=0.f,S1i=0.f,S2r=0.f,S2i=0.f;
  #pragma unroll
  for (int j=0;j<8;++j){
    S1r += qre[j]; S1i += qim[j];
    S2r += qre[j]*qre[j]-qim[j]*qim[j];
    S2i += 2.f*qre[j]*qim[j];
  }
  wreduce4(S1r,S1i,S2r,S2i);
  float myr = S1r*(1.f/512.f), myi = S1i*(1.f/512.f);
  float bsr = S2r - (S1r*myr - S1i*myi);
  float bsi = S2i - (S1r*myi + S1i*myr);

  size_t obase = ((size_t)((b*KN)*2048 + l))*512 + lane*8;
  const size_t kstride = (size_t)2048*512;

  // k=0
  process_k(vr, vi, qre,qim, myr,myi,bsr,bsi, stw_r,stw_i,btw_r,btw_i, lane,
            outs + obase);
  // ---- packed FFT P2: c1 + i*c2 ----
  fft512_fwd(c1, c2, stw_r,stw_i,btw_r,btw_i, lane);
  rfft_separate(c1, c2, qv, c0, vr, vi, plane, lane);   // A->(qv,c0)=vf1, B->(vr,vi)=vf2
  process_k(qv, c0, qre,qim, myr,myi,bsr,bsi, stw_r,stw_i,btw_r,btw_i, lane,
            outs + obase + kstride);
  process_k(vr, vi, qre,qim, myr,myi,bsr,bsi, stw_r,stw_i,btw_r,btw_i, lane,
            outs + obase + 2*kstride);
  // ---- FFT P3: c3 (real, no pack) ----
  #pragma unroll
  for (int j=0;j<8;++j) c2[j]=0.f;
  fft512_fwd(c3, c2, stw_r,stw_i,btw_r,btw_i, lane);
  process_k(c3, c2, qre,qim, myr,myi,bsr,bsi, stw_r,stw_i,btw_r,btw_i, lane,
            outs + obase + 3*kstride);
}

// scores[b,c,k] = sum_l qmean[b,l] * outs[b,k,l,c]
__global__ __launch_bounds__(256) void scores_kernel(
    const unsigned short* __restrict__ outs, const float* __restrict__ qmean,
    float* __restrict__ scores)
{
  int tid = threadIdx.x;
  int l0 = blockIdx.x*128;
  int k = blockIdx.y;
  int b = blockIdx.z;
  int c = tid*2;
  float accx=0.f, accy=0.f;
  for (int l=l0; l<l0+128; ++l){
    float s = qmean[b*2048+l];
    const unsigned short* p = outs + ((size_t)((b*KN+k)*2048 + l))*512 + c;
    unsigned int u = *(const unsigned int*)p;
    accx += s*bf2f((unsigned short)(u&0xffffu));
    accy += s*bf2f((unsigned short)(u>>16));
  }
  atomicAdd(&scores[(size_t)(b*512+c)*KN + k], accx);
  atomicAdd(&scores[(size_t)(b*512+c+1)*KN + k], accy);
}

// out[b,c,l] = sum_k softmax_k(scores[b,c,:]) * outs[b,k,l,c]
__global__ __launch_bounds__(256) void combine_kernel(
    const unsigned short* __restrict__ outs, const float* __restrict__ scores,
    float* __restrict__ out)
{
  __shared__ float wa[64][KN];
  int cx = threadIdx.x;      // 64
  int ly = threadIdx.y;      // 4
  int l0 = blockIdx.x*64;
  int c  = blockIdx.y*64 + cx;
  int b  = blockIdx.z;
  if (ly==0){
    float4 s = *reinterpret_cast<const float4*>(&scores[(size_t)(b*512+c)*KN]);
    float m = fmaxf(fmaxf(s.x,s.y),fmaxf(s.z,s.w));
    float e0=expf(s.x-m), e1=expf(s.y-m), e2=expf(s.z-m), e3=expf(s.w-m);
    float inv = 1.f/(e0+e1+e2+e3);
    wa[cx][0]=e0*inv; wa[cx][1]=e1*inv; wa[cx][2]=e2*inv; wa[cx][3]=e3*inv;
  }
  __syncthreads();
  float acc[16];
  #pragma unroll
  for (int i=0;i<16;++i) acc[i]=0.f;
  for (int k=0;k<KN;++k){
    float w = wa[cx][k];
    const unsigned short* p = outs + ((size_t)((b*KN+k)*2048) + l0 + ly*16)*512 + c;
    #pragma unroll
    for (int i=0;i<16;++i){
      acc[i] += w*bf2f(p[(size_t)i*512]);
    }
  }
  float* op = out + ((size_t)(b*512+c))*2048 + l0 + ly*16;
  #pragma unroll
  for (int i=0;i<16;i+=4){
    float4 v = make_float4(acc[i],acc[i+1],acc[i+2],acc[i+3]);
    *reinterpret_cast<float4*>(op+i) = v;
  }
}

extern "C" void kernel_launch(void* const* d_in, const int* in_sizes, int n_in,
                              void* d_out, int out_size, void* d_ws, size_t ws_size,
                              hipStream_t stream)
{
  const float* x   = (const float*)d_in[0];
  const float* q   = (const float*)d_in[1];
  const float* sig = (const float*)d_in[2];
  const float* cen = (const float*)d_in[3];
  const int*   ksp = (const int*)d_in[4];
  float* out = (float*)d_out;

  unsigned short* outs = (unsigned short*)d_ws;
  size_t outs_elems = (size_t)B_DIM*KN*L_DIM*C_DIM;
  float* qmeanb = (float*)((char*)d_ws + outs_elems*sizeof(unsigned short));
  float* scores = qmeanb + (size_t)B_DIM*L_DIM;

  hipMemsetAsync(scores, 0, (size_t)B_DIM*C_DIM*KN*sizeof(float), stream);

  dim3 g1(B_DIM*L_DIM/4);
  hipLaunchKernelGGL(col_kernel, g1, dim3(256), 0, stream,
                     x, q, sig, cen, ksp, outs, qmeanb);
  dim3 g2(L_DIM/128, KN, B_DIM);
  hipLaunchKernelGGL(scores_kernel, g2, dim3(256), 0, stream, outs, qmeanb, scores);
  dim3 g3(L_DIM/64, C_DIM/64, B_DIM);
  hipLaunchKernelGGL(combine_kernel, g3, dim3(64,4), 0, stream, outs, scores, out);
}

// Round 4
// 236.400 us; speedup vs baseline: 1.6911x; 1.0583x over previous
//
#include <hip/hip_runtime.h>
#include <hip/hip_bf16.h>

#define B_DIM 4
#define C_DIM 512
#define L_DIM 2048
#define KN 4
#define MAXKS 9

__device__ inline float bf2f(unsigned short u){ return __uint_as_float(((unsigned)u)<<16); }
__device__ inline unsigned short f2bf(float f){
  unsigned u = __float_as_uint(f);
  unsigned r = (u + 0x7fffu + ((u>>16)&1u))>>16;
  return (unsigned short)r;
}

// branchless atan2, ~1e-5 rad abs error
__device__ __forceinline__ float fast_atan2(float y, float x){
  float ax = fabsf(x), ay = fabsf(y);
  float mx = fmaxf(ax, ay), mn = fminf(ax, ay);
  float t = __fdividef(mn, mx);                 // mx==0 -> NaN -> caught by wm guard
  float a = t*t;
  float r = t*(0.9998660f + a*(-0.3302995f + a*(0.1801410f + a*(-0.0851330f + a*0.0208351f))));
  r = (ay > ax) ? 1.5707963267948966f - r : r;
  r = (x < 0.f) ? 3.14159265358979323846f - r : r;
  return copysignf(r, y);
}
// tanh(u) = (e^{2u}-1)/(e^{2u}+1), one native v_exp
__device__ __forceinline__ float fast_tanh(float u){
  float e = exp2f(2.8853900817779268f*u);       // e^{2u}
  return __fdividef(e-1.f, e+1.f);
}

// ---------- wave-level 512-pt FFT: 64 lanes x 8 regs ----------
// time layout : lane l, slot j holds x[8*l + j]
// freq layout : lane l, slot j holds X[rev6(l) + 64*j]
__device__ __forceinline__ void lane_fft_fwd(float* zr, float* zi,
                                             const float* stw_r, const float* stw_i, int lane){
  #pragma unroll
  for (int s=5; s>=0; --s){
    int m = 1<<s;
    bool hi = (lane & m) != 0;
    float wr = stw_r[s], wi = stw_i[s];
    #pragma unroll
    for (int j=0;j<8;++j){
      float pr = __shfl_xor(zr[j], m);
      float pi = __shfl_xor(zi[j], m);
      float sr = hi ? (pr - zr[j]) : (zr[j] + pr);
      float si = hi ? (pi - zi[j]) : (zi[j] + pi);
      float mr = sr*wr - si*wi;
      float mi = sr*wi + si*wr;
      zr[j] = hi ? mr : sr;
      zi[j] = hi ? mi : si;
    }
  }
}

__device__ __forceinline__ void lane_fft_inv(float* zr, float* zi,
                                             const float* stw_r, const float* stw_i, int lane){
  #pragma unroll
  for (int s=0; s<6; ++s){
    int m = 1<<s;
    bool hi = (lane & m) != 0;
    float wr = stw_r[s], wi = -stw_i[s];
    #pragma unroll
    for (int j=0;j<8;++j){
      float pr = __shfl_xor(zr[j], m);
      float pi = __shfl_xor(zi[j], m);
      float ar = hi ? zr[j] : pr;
      float ai = hi ? zi[j] : pi;
      float mr = ar*wr - ai*wi;
      float mi = ar*wi + ai*wr;
      zr[j] = hi ? (pr - mr) : (zr[j] + mr);
      zi[j] = hi ? (pi - mi) : (zi[j] + mi);
    }
  }
}

__device__ __forceinline__ void fft8_reg(float* zr, float* zi, float sgn){
  const float C = 0.70710678118654752f;
  float s0r=zr[0]+zr[4], s0i=zi[0]+zi[4];
  float s1r=zr[0]-zr[4], s1i=zi[0]-zi[4];
  float s2r=zr[2]+zr[6], s2i=zi[2]+zi[6];
  float s3r=zr[2]-zr[6], s3i=zi[2]-zi[6];
  float e0r=s0r+s2r, e0i=s0i+s2i;
  float e2r=s0r-s2r, e2i=s0i-s2i;
  float j3r=-sgn*s3i, j3i=sgn*s3r;
  float e1r=s1r+j3r, e1i=s1i+j3i;
  float e3r=s1r-j3r, e3i=s1i-j3i;
  float t0r=zr[1]+zr[5], t0i=zi[1]+zi[5];
  float t1r=zr[1]-zr[5], t1i=zi[1]-zi[5];
  float t2r=zr[3]+zr[7], t2i=zi[3]+zi[7];
  float t3r=zr[3]-zr[7], t3i=zi[3]-zi[7];
  float o0r=t0r+t2r, o0i=t0i+t2i;
  float o2r=t0r-t2r, o2i=t0i-t2i;
  float k3r=-sgn*t3i, k3i=sgn*t3r;
  float o1r=t1r+k3r, o1i=t1i+k3i;
  float o3r=t1r-k3r, o3i=t1i-k3i;
  float w1o_r = C*o1r - sgn*C*o1i;
  float w1o_i = C*o1i + sgn*C*o1r;
  float w2o_r = -sgn*o2i, w2o_i = sgn*o2r;
  float w3o_r = -C*o3r - sgn*C*o3i;
  float w3o_i = -C*o3i + sgn*C*o3r;
  zr[0]=e0r+o0r;   zi[0]=e0i+o0i;
  zr[4]=e0r-o0r;   zi[4]=e0i-o0i;
  zr[1]=e1r+w1o_r; zi[1]=e1i+w1o_i;
  zr[5]=e1r-w1o_r; zi[5]=e1i-w1o_i;
  zr[2]=e2r+w2o_r; zi[2]=e2i+w2o_i;
  zr[6]=e2r-w2o_r; zi[6]=e2i-w2o_i;
  zr[3]=e3r+w3o_r; zi[3]=e3i+w3o_i;
  zr[7]=e3r-w3o_r; zi[7]=e3i-w3o_i;
}

__device__ __forceinline__ void fft512_fwd(float* zr, float* zi,
    const float* stw_r, const float* stw_i,
    const float* btw_r, const float* btw_i, int lane){
  lane_fft_fwd(zr, zi, stw_r, stw_i, lane);
  #pragma unroll
  for (int j=1;j<8;++j){
    float ar=zr[j], ai=zi[j];
    zr[j]=ar*btw_r[j]-ai*btw_i[j];
    zi[j]=ar*btw_i[j]+ai*btw_r[j];
  }
  fft8_reg(zr, zi, -1.f);
}

__device__ __forceinline__ void fft512_inv(float* zr, float* zi,
    const float* stw_r, const float* stw_i,
    const float* btw_r, const float* btw_i, int lane){
  fft8_reg(zr, zi, +1.f);
  #pragma unroll
  for (int j=1;j<8;++j){
    float ar=zr[j], ai=zi[j];
    zr[j]= ar*btw_r[j]+ai*btw_i[j];
    zi[j]=-ar*btw_i[j]+ai*btw_r[j];
  }
  lane_fft_inv(zr, zi, stw_r, stw_i, lane);
}

// Unpack two real-signal spectra from one packed complex FFT.
// A[k]=(Z[k]+conj(Z[N-k]))/2 ; B[k]=(Z[k]-conj(Z[N-k]))/(2i)
// bin(lane,j)=rev6(lane)+64j ; partner at lane plane, slot 7-j (lane0: self, slot (8-j)&7)
__device__ __forceinline__ void rfft_separate(const float* zr, const float* zi,
    float* ar, float* ai, float* br, float* bi, int plane, int lane){
  #pragma unroll
  for (int j=0;j<8;++j){
    const int js = 7-j;
    const int j0 = (8-j)&7;
    float pr = __shfl(zr[js], plane);
    float pi = __shfl(zi[js], plane);
    pr = (lane==0) ? zr[j0] : pr;
    pi = (lane==0) ? zi[j0] : pi;
    ar[j] = 0.5f*(zr[j]+pr);
    ai[j] = 0.5f*(zi[j]-pi);
    br[j] = 0.5f*(zi[j]+pi);
    bi[j] = 0.5f*(pr-zr[j]);
  }
}

__device__ __forceinline__ void wreduce4(float&a,float&b,float&c,float&d){
  #pragma unroll
  for (int off=1; off<64; off<<=1){
    a += __shfl_xor(a,off); b += __shfl_xor(b,off);
    c += __shfl_xor(c,off); d += __shfl_xor(d,off);
  }
}

// stats -> correlation weight -> filter -> iFFT -> bf16 store (in place on vr/vi)
__device__ __forceinline__ void process_k(float* vr, float* vi,
    const float* qre, const float* qim,
    float myr, float myi, float bsr, float bsi,
    const float* stw_r, const float* stw_i,
    const float* btw_r, const float* btw_i,
    int lane, unsigned short* outp)
{
  float T1r=0.f,T1i=0.f,T2r=0.f,T2i=0.f;
  #pragma unroll
  for (int j=0;j<8;++j){
    T1r += vr[j]; T1i += vi[j];
    T2r += vr[j]*vr[j]-vi[j]*vi[j];
    T2i += 2.f*vr[j]*vi[j];
  }
  wreduce4(T1r,T1i,T2r,T2i);
  float mxr = T1r*(1.f/512.f), mxi = T1i*(1.f/512.f);
  float asr = T2r - (T1r*mxr - T1i*mxi);
  float asi = T2i - (T1r*mxi + T1i*mxr);
  float zr_ = asr*bsr - asi*bsi + 1.0e-4f;
  float zi_ = asr*bsi + asi*bsr;
  float rmag = sqrtf(zr_*zr_+zi_*zi_);
  float dr = sqrtf(fmaxf(0.5f*(rmag+zr_),0.f));
  float di = sqrtf(fmaxf(0.5f*(rmag-zr_),0.f));
  di = (zi_ < 0.f) ? -di : di;
  float den = dr*dr + di*di;
  float invden = __fdividef(1.f, den);
  float invr = (den>0.f) ? dr*invden : 0.f;
  float invi = (den>0.f) ? -di*invden : 0.f;

  #pragma unroll
  for (int j=0;j<8;++j){
    float vr_=vr[j], vi_=vi[j], qr_=qre[j], qi_=qim[j];
    float dxr = vr_-mxr, dxi = vi_-mxi;
    float dyr = qr_-myr, dyi = qi_-myi;
    float cvr = dxr*dyr - dxi*dyi;
    float cvi = dxr*dyi + dxi*dyr;
    float rr = cvr*invr - cvi*invi;
    float ri = cvr*invi + cvi*invr;
    float ang = fast_atan2(ri, rr + 1.0e-4f);
    float wm  = fast_tanh(ang*0.25f);
    if (!(wm==wm)) wm = 0.f;
    float fdr = vr_-qr_, fdi = vi_-qi_;
    float fd2 = fdr*fdr+fdi*fdi;
    float w = exp2f(-0.72134752044448170f*fd2)*wm;   // exp(-0.5*fd2)
    vr[j] = qr_ + w*fdr;
    vi[j] = qi_ + w*fdi;
  }

  fft512_inv(vr,vi,stw_r,stw_i,btw_r,btw_i,lane);

  unsigned short ob[8];
  #pragma unroll
  for (int j=0;j<8;++j){
    float mag = sqrtf(vr[j]*vr[j]+vi[j]*vi[j])*(1.f/512.f);
    ob[j] = f2bf(mag);
  }
  uint4 pk;
  pk.x = (unsigned)ob[0] | ((unsigned)ob[1]<<16);
  pk.y = (unsigned)ob[2] | ((unsigned)ob[3]<<16);
  pk.z = (unsigned)ob[4] | ((unsigned)ob[5]<<16);
  pk.w = (unsigned)ob[6] | ((unsigned)ob[7]<<16);
  *reinterpret_cast<uint4*>(outp) = pk;
}

__global__ __launch_bounds__(256,3) void col_kernel(
    const float* __restrict__ x, const float* __restrict__ q,
    const float* __restrict__ sigmas, const float* __restrict__ centers,
    const int* __restrict__ ksp,
    unsigned short* __restrict__ outs, float* __restrict__ qmean)
{
  __shared__ float kern[KN][MAXKS];
  int tid  = threadIdx.x;
  int wave = tid >> 6;
  int lane = tid & 63;
  // XCD-aware bijective swizzle: 2048 blocks, 8 XCDs, 256 blocks/XCD contiguous.
  // Consecutive l-columns share 64B lines of x/q; this keeps them on one XCD's L2.
  int bid  = blockIdx.x;
  int swz  = (bid & 7)*((B_DIM*L_DIM/4)/8) + (bid >> 3);
  int col  = swz*4 + wave;                 // col = b*2048 + l
  int b = col >> 11;
  int l = col & 2047;
  int ks  = ksp[0];
  int pad = ks >> 1;

  if (tid < KN){
    float half = 0.5f*(float)(ks-1);
    float sg = sigmas[tid] + 0.001f;
    float ce = centers[tid];
    float s = 0.f;
    for (int t=0;t<ks;++t){ float d=((float)t-half-ce)/sg; s += expf(-0.5f*d*d); }
    float inv = 1.f/(s+0.01f);
    for (int t=0;t<ks;++t){ float d=((float)t-half-ce)/sg; kern[tid][t] = expf(-0.5f*d*d)*inv; }
  }

  // ---- issue q loads early (latency cover under twiddle setup) ----
  float qv[8];
  const float* qbase = q + ((size_t)(b*512) + lane*8)*2048 + l;
  #pragma unroll
  for (int j=0;j<8;++j) qv[j] = qbase[(size_t)j*2048];

  const float PI = 3.14159265358979323846f;
  int k1 = (int)(__brev((unsigned)lane) >> 26);
  int plane; { int pk_ = (64-k1)&63; plane = (int)(__brev((unsigned)pk_)>>26); }

  float stw_r[6], stw_i[6];
  #pragma unroll
  for (int s=0; s<6; ++s){
    int m = 1<<s;
    float ang = -PI * (float)(lane & (m-1)) / (float)m;
    stw_r[s]=__cosf(ang); stw_i[s]=__sinf(ang);
  }
  float btw_r[8], btw_i[8];
  #pragma unroll
  for (int j=0;j<8;++j){
    float ang = -2.f*PI*(float)(j*k1)/512.f;
    btw_r[j]=__cosf(ang); btw_i[j]=__sinf(ang);
  }

  __syncthreads();                          // kern ready

  float c0[8], c1[8], c2[8], c3[8];
  #pragma unroll
  for (int j=0;j<8;++j){ c0[j]=0.f; c1[j]=0.f; c2[j]=0.f; c3[j]=0.f; }
  const float* xbase = x + ((size_t)(b*512) + lane*8)*2048;
  for (int t=0;t<ks;++t){
    int li = l + t - pad;
    li = li<0 ? 0 : (li>2047 ? 2047 : li);
    float w0=kern[0][t], w1=kern[1][t], w2=kern[2][t], w3=kern[3][t];
    #pragma unroll
    for (int j=0;j<8;++j){
      float xv = xbase[(size_t)j*2048 + li];
      c0[j] += w0*xv; c1[j] += w1*xv; c2[j] += w2*xv; c3[j] += w3*xv;
    }
  }

  // ---- packed FFT P1: q + i*c0 ----
  fft512_fwd(qv, c0, stw_r,stw_i,btw_r,btw_i, lane);
  float qre[8], qim[8], vr[8], vi[8];
  rfft_separate(qv, c0, qre, qim, vr, vi, plane, lane);

  if (lane==0) qmean[b*2048+l] = qre[0]*(1.f/512.f);

  float S1r=0.f,S1i=0.f,S2r=0.f,S2i=0.f;
  #pragma unroll
  for (int j=0;j<8;++j){
    S1r += qre[j]; S1i += qim[j];
    S2r += qre[j]*qre[j]-qim[j]*qim[j];
    S2i += 2.f*qre[j]*qim[j];
  }
  wreduce4(S1r,S1i,S2r,S2i);
  float myr = S1r*(1.f/512.f), myi = S1i*(1.f/512.f);
  float bsr = S2r - (S1r*myr - S1i*myi);
  float bsi = S2i - (S1r*myi + S1i*myr);

  size_t obase = ((size_t)((b*KN)*2048 + l))*512 + lane*8;
  const size_t kstride = (size_t)2048*512;

  // k=0
  process_k(vr, vi, qre,qim, myr,myi,bsr,bsi, stw_r,stw_i,btw_r,btw_i, lane,
            outs + obase);
  // ---- packed FFT P2: c1 + i*c2 ----
  fft512_fwd(c1, c2, stw_r,stw_i,btw_r,btw_i, lane);
  rfft_separate(c1, c2, qv, c0, vr, vi, plane, lane);   // A->(qv,c0)=vf1, B->(vr,vi)=vf2
  process_k(qv, c0, qre,qim, myr,myi,bsr,bsi, stw_r,stw_i,btw_r,btw_i, lane,
            outs + obase + kstride);
  process_k(vr, vi, qre,qim, myr,myi,bsr,bsi, stw_r,stw_i,btw_r,btw_i, lane,
            outs + obase + 2*kstride);
  // ---- FFT P3: c3 (real, no pack) ----
  #pragma unroll
  for (int j=0;j<8;++j) c2[j]=0.f;
  fft512_fwd(c3, c2, stw_r,stw_i,btw_r,btw_i, lane);
  process_k(c3, c2, qre,qim, myr,myi,bsr,bsi, stw_r,stw_i,btw_r,btw_i, lane,
            outs + obase + 3*kstride);
}

// scores[b,c,k] = sum_l qmean[b,l] * outs[b,k,l,c]
__global__ __launch_bounds__(256) void scores_kernel(
    const unsigned short* __restrict__ outs, const float* __restrict__ qmean,
    float* __restrict__ scores)
{
  int tid = threadIdx.x;
  int l0 = blockIdx.x*128;
  int k = blockIdx.y;
  int b = blockIdx.z;
  int c = tid*2;
  float accx=0.f, accy=0.f;
  for (int l=l0; l<l0+128; ++l){
    float s = qmean[b*2048+l];
    const unsigned short* p = outs + ((size_t)((b*KN+k)*2048 + l))*512 + c;
    unsigned int u = *(const unsigned int*)p;
    accx += s*bf2f((unsigned short)(u&0xffffu));
    accy += s*bf2f((unsigned short)(u>>16));
  }
  atomicAdd(&scores[(size_t)(b*512+c)*KN + k], accx);
  atomicAdd(&scores[(size_t)(b*512+c+1)*KN + k], accy);
}

// out[b,c,l] = sum_k softmax_k(scores[b,c,:]) * outs[b,k,l,c]
__global__ __launch_bounds__(256) void combine_kernel(
    const unsigned short* __restrict__ outs, const float* __restrict__ scores,
    float* __restrict__ out)
{
  __shared__ float wa[64][KN];
  int cx = threadIdx.x;      // 64
  int ly = threadIdx.y;      // 4
  int l0 = blockIdx.x*64;
  int c  = blockIdx.y*64 + cx;
  int b  = blockIdx.z;
  if (ly==0){
    float4 s = *reinterpret_cast<const float4*>(&scores[(size_t)(b*512+c)*KN]);
    float m = fmaxf(fmaxf(s.x,s.y),fmaxf(s.z,s.w));
    float e0=expf(s.x-m), e1=expf(s.y-m), e2=expf(s.z-m), e3=expf(s.w-m);
    float inv = 1.f/(e0+e1+e2+e3);
    wa[cx][0]=e0*inv; wa[cx][1]=e1*inv; wa[cx][2]=e2*inv; wa[cx][3]=e3*inv;
  }
  __syncthreads();
  float acc[16];
  #pragma unroll
  for (int i=0;i<16;++i) acc[i]=0.f;
  for (int k=0;k<KN;++k){
    float w = wa[cx][k];
    const unsigned short* p = outs + ((size_t)((b*KN+k)*2048) + l0 + ly*16)*512 + c;
    #pragma unroll
    for (int i=0;i<16;++i){
      acc[i] += w*bf2f(p[(size_t)i*512]);
    }
  }
  float* op = out + ((size_t)(b*512+c))*2048 + l0 + ly*16;
  #pragma unroll
  for (int i=0;i<16;i+=4){
    float4 v = make_float4(acc[i],acc[i+1],acc[i+2],acc[i+3]);
    *reinterpret_cast<float4*>(op+i) = v;
  }
}

extern "C" void kernel_launch(void* const* d_in, const int* in_sizes, int n_in,
                              void* d_out, int out_size, void* d_ws, size_t ws_size,
                              hipStream_t stream)
{
  const float* x   = (const float*)d_in[0];
  const float* q   = (const float*)d_in[1];
  const float* sig = (const float*)d_in[2];
  const float* cen = (const float*)d_in[3];
  const int*   ksp = (const int*)d_in[4];
  float* out = (float*)d_out;

  unsigned short* outs = (unsigned short*)d_ws;
  size_t outs_elems = (size_t)B_DIM*KN*L_DIM*C_DIM;
  float* qmeanb = (float*)((char*)d_ws + outs_elems*sizeof(unsigned short));
  float* scores = qmeanb + (size_t)B_DIM*L_DIM;

  hipMemsetAsync(scores, 0, (size_t)B_DIM*C_DIM*KN*sizeof(float), stream);

  dim3 g1(B_DIM*L_DIM/4);
  hipLaunchKernelGGL(col_kernel, g1, dim3(256), 0, stream,
                     x, q, sig, cen, ksp, outs, qmeanb);
  dim3 g2(L_DIM/128, KN, B_DIM);
  hipLaunchKernelGGL(scores_kernel, g2, dim3(256), 0, stream, outs, qmeanb, scores);
  dim3 g3(L_DIM/64, C_DIM/64, B_DIM);
  hipLaunchKernelGGL(combine_kernel, g3, dim3(64,4), 0, stream, outs, scores, out);
}